// Round 9
// baseline (20.232 us; speedup 1.0000x reference)
//
#include <hip/hip_runtime.h>
#include <math.h>

#define EPSF 1e-7f

__constant__ float c_anch[3][3][2] = {
    {{80.f,104.f},{128.f,240.f},{264.f,184.f}},
    {{480.f,976.f},{992.f,720.f},{944.f,1904.f}},
    {{3712.f,2880.f},{4992.f,6336.f},{11936.f,10432.f}}
};
__constant__ float c_stride[3] = {8.f, 16.f, 32.f};
__constant__ float c_bal[3]    = {4.f, 1.f, 0.4f};
__constant__ int   c_HW[3]     = {6400, 1600, 400};
__constant__ int   c_W[3]      = {80, 40, 20};

__device__ __forceinline__ float bce0(float x) {
    // BCE with target 0: max(x,0) + log(1+exp(-|x|))
    return fmaxf(x, 0.f) + __logf(1.f + __expf(-fabsf(x)));
}

// key-only target build (no logs) — used for the per-block npos recompute
__device__ __forceinline__ int buildKey(float4 bx, int s) {
    float cx = (bx.x + bx.z) * 0.5f, cy = (bx.y + bx.w) * 0.5f;
    float w  = bx.z - bx.x,          h  = bx.w - bx.y;
    float stride = c_stride[s];
    int W = c_W[s];
    int gi = min(max((int)(cy / stride), 0), W - 1);   // row from y
    int gj = min(max((int)(cx / stride), 0), W - 1);   // col from x
    int best = 0; float bm = 1e30f;
    for (int k = 0; k < 3; ++k) {
        float aw = c_anch[s][k][0], ah = c_anch[s][k][1];
        float r0 = w / aw, r1 = h / ah;
        float m = fmaxf(r0, 1.f / r0) * fmaxf(r1, 1.f / r1);
        if (m < bm) { bm = m; best = k; }
    }
    return (best << 20) | (gi << 10) | gj;
}

// ---------------------------------------------------------------------------
// Single compute kernel (400 blocks x 256) + a memset node for out[0]=0:
//   all blocks      : 252-float4 slice of the dense objectness reduce
//   blocks [0,384)  : positive targets (register build, no barrier) and an
//                     independent per-block npos[s] recompute (inputs-only)
//   each block ends with ONE device-scope atomicAdd(out, contribution/16)
// ---------------------------------------------------------------------------
__global__ __launch_bounds__(256) void fused_all(
        const float* __restrict__ p0, const float* __restrict__ p1,
        const float* __restrict__ p2,
        const float* __restrict__ boxes, const int* __restrict__ labels,
        float* __restrict__ out)
{
    __shared__ float red[4][5];          // per-wave {dsum, box, objc, cls, np}

    const int bid  = blockIdx.x;
    const int tid  = threadIdx.x;
    const int lane = tid & 63, wv = tid >> 6;

    const bool isPos = (bid < 384);
    const int s   = bid >> 7;            // valid for pos blocks
    const int b   = (bid >> 3) & 15;
    const int grp = bid & 7;             // target n = grp*4 + wave

    // ---- issue all boxes/labels loads first (pos blocks) ----
    float4 bx; int labl = 0;
    float4 bxn0, bxn1;                   // npos rounds: wave wv covers batches 4wv..4wv+3
    if (isPos) {
        if (lane < 32) {
            bx   = ((const float4*)boxes)[b * 32 + lane];
            labl = labels[b * 32 + lane];
        }
        bxn0 = ((const float4*)boxes)[(wv * 4 + 0 + (lane >> 5)) * 32 + (lane & 31)];
        bxn1 = ((const float4*)boxes)[(wv * 4 + 2 + (lane >> 5)) * 32 + (lane & 31)];
    }

    // ---------------- dense objectness slice (all blocks) ----------------
    float dsum = 0.f;
    {
        int v = bid * 252 + tid;                 // 400*252 = 100800 exactly
        if (tid < 252) {
            int sc, run, off, HW;
            const float* pred;
            if (v < 76800)      { sc = 0; HW = 6400; run = v / 1600;          off = v - run * 1600;         pred = p0; }
            else if (v < 96000) { sc = 1; HW = 1600; int u = v - 76800; run = u / 400; off = u - run * 400; pred = p1; }
            else                { sc = 2; HW = 400;  int u = v - 96000; run = u / 100; off = u - run * 100; pred = p2; }
            int bb = run / 3, a = run - bb * 3;
            const float4* ptr = (const float4*)(pred + (size_t)(bb * 255 + a * 85 + 4) * HW) + off;
            float4 x = *ptr;
            float w = 0.5f * c_bal[sc];
            dsum = w * (bce0(x.x) + bce0(x.y) + bce0(x.z) + bce0(x.w));
        }
    }

    float boxc = 0.f, objc = 0.f, clsp = 0.f;
    float npw = 0.f;                      // this wave's npos contribution (4 batches)
    if (isPos) {
        // ---- per-block npos recompute: 2 rounds x 2 half-wave batches ----
        {
            const int l32 = lane & 31, base = lane & 32;
            int k0 = buildKey(bxn0, s);
            bool dup = false;
            for (int d = 1; d < 32; ++d) {
                int nk = __shfl(k0, base + ((l32 + d) & 31));
                dup |= ((l32 + d) < 32) && (nk == k0);
            }
            npw += (float)__popcll(__ballot(!dup));
            int k1 = buildKey(bxn1, s);
            dup = false;
            for (int d = 1; d < 32; ++d) {
                int nk = __shfl(k1, base + ((l32 + d) & 31));
                dup |= ((l32 + d) < 32) && (nk == k1);
            }
            npw += (float)__popcll(__ballot(!dup));
        }

        // ---- register target build (lanes < 32 hold target `lane`) ----
        int key = 0; float txl = 0.f, tyl = 0.f, twl = 0.f, thl = 0.f;
        {
            float cx = (bx.x + bx.z) * 0.5f, cy = (bx.y + bx.w) * 0.5f;
            float w  = bx.z - bx.x,          h  = bx.w - bx.y;
            float stride = c_stride[s];
            float xg = cx / stride, yg = cy / stride;
            int W = c_W[s];
            int gi = min(max((int)yg, 0), W - 1);   // row from y
            int gj = min(max((int)xg, 0), W - 1);   // col from x
            int best = 0; float bm = 1e30f;
            for (int k = 0; k < 3; ++k) {
                float aw = c_anch[s][k][0], ah = c_anch[s][k][1];
                float r0 = w / aw, r1 = h / ah;
                float m = fmaxf(r0, 1.f / r0) * fmaxf(r1, 1.f / r1);
                if (m < bm) { bm = m; best = k; }
            }
            float aw = c_anch[s][best][0], ah = c_anch[s][best][1];
            key = (best << 20) | (gi << 10) | gj;
            txl = xg - (float)gj;
            tyl = yg - (float)gi;
            twl = __logf(w / (aw + 1e-16f));
            thl = __logf(h / (ah + 1e-16f));
        }

        // this wave's target n: broadcast from lane n, dedup via one ballot
        const int n = grp * 4 + wv;
        int   key_n = __shfl(key, n);
        float tx_n  = __shfl(txl, n);
        float ty_n  = __shfl(tyl, n);
        float tw_n  = __shfl(twl, n);
        float th_n  = __shfl(thl, n);
        int   lab   = __shfl(labl, n);
        unsigned long long dupm =
            __ballot((lane > n) && (lane < 32) && (key == key_n));
        bool win = (dupm == 0ull);        // last-n-wins scatter semantics

        if (win) {
            int a  = key_n >> 20;
            int gi = (key_n >> 10) & 1023;
            int gj = key_n & 1023;
            const int HW = c_HW[s], W = c_W[s];
            int hw = gi * W + gj;
            const float* pred = (s == 0) ? p0 : ((s == 1) ? p1 : p2);
            const float* pb_ = pred + (size_t)(b * 255 + a * 85) * HW + hw;
            const float* pc  = pb_ + (size_t)5 * HW;

            // lane-parallel class logit loads
            float xc0 = pc[(size_t)lane * HW];
            float xc1 = (lane < 16) ? pc[(size_t)(lane + 64) * HW] : 0.f;
            clsp = bce0(xc0) - ((lane == lab) ? xc0 : 0.f);
            if (lane < 16) clsp += bce0(xc1) - ((lane + 64 == lab) ? xc1 : 0.f);

            float px = pb_[0], py = pb_[(size_t)HW];
            float pw = pb_[2 * (size_t)HW], ph = pb_[3 * (size_t)HW];
            float xo = pb_[4 * (size_t)HW];

            // objectness correction:  bal * (0.5*bce0(xo) - xo)
            objc = c_bal[s] * (0.5f * bce0(xo) - xo);

            // CIoU (lane-redundant)
            const float stride = c_stride[s];
            const float aw = c_anch[s][a][0], ah = c_anch[s][a][1];
            float sx = 1.f / (1.f + __expf(-px));
            float sy = 1.f / (1.f + __expf(-py));
            float b1x = (sx + (float)gj) * stride, b1y = (sy + (float)gi) * stride;
            float b1w = __expf(pw) * aw,           b1h = __expf(ph) * ah;
            float b2x = ((float)gj + tx_n) * stride, b2y = ((float)gi + ty_n) * stride;
            float b2w = __expf(tw_n) * aw,           b2h = __expf(th_n) * ah;

            float b1x1 = b1x - b1w * 0.5f, b1x2 = b1x + b1w * 0.5f;
            float b1y1 = b1y - b1h * 0.5f, b1y2 = b1y + b1h * 0.5f;
            float b2x1 = b2x - b2w * 0.5f, b2x2 = b2x + b2w * 0.5f;
            float b2y1 = b2y - b2h * 0.5f, b2y2 = b2y + b2h * 0.5f;
            float iw = fmaxf(fminf(b1x2, b2x2) - fmaxf(b1x1, b2x1), 0.f);
            float ih = fmaxf(fminf(b1y2, b2y2) - fmaxf(b1y1, b2y1), 0.f);
            float inter = iw * ih;
            float uni = b1w * b1h + b2w * b2h - inter + EPSF;
            float iou = inter / uni;
            float cwv = fmaxf(b1x2, b2x2) - fminf(b1x1, b2x1);
            float chv = fmaxf(b1y2, b2y2) - fminf(b1y1, b2y1);
            float c2 = cwv * cwv + chv * chv + EPSF;
            float dx = b2x1 + b2x2 - b1x1 - b1x2;
            float dy = b2y1 + b2y2 - b1y1 - b1y2;
            float rho2 = (dx * dx + dy * dy) * 0.25f;
            float dat = atanf(b2w / (b2h + EPSF)) - atanf(b1w / (b1h + EPSF));
            float v = (4.f / (float)(M_PI * M_PI)) * dat * dat;
            float alpha = v / (v - iou + 1.f + EPSF);
            boxc = 1.f - (iou - (rho2 / c2 + v * alpha));
        }
    }

    // block reduce: {dsum, box, objc, cls, np} -> one scalar per block
    for (int o = 32; o > 0; o >>= 1) {
        dsum += __shfl_down(dsum, o);
        clsp += __shfl_down(clsp, o);
    }
    if (lane == 0) {
        red[wv][0] = dsum; red[wv][1] = boxc; red[wv][2] = objc;
        red[wv][3] = clsp; red[wv][4] = npw;
    }
    __syncthreads();
    if (tid == 0) {
        float d = 0.f, bxs = 0.f, oc = 0.f, cl = 0.f, np = 0.f;
        for (int i = 0; i < 4; ++i) {
            d  += red[i][0]; bxs += red[i][1]; oc += red[i][2];
            cl += red[i][3]; np  += red[i][4];
        }
        // dense blocks: bxs=0, np=0 -> box term 0/1 = 0
        float contrib = d + oc + 0.5f * cl + bxs / fmaxf(np, 1.f);
        atomicAdd(out, contrib * 0.0625f);   // / B (=16)
    }
}

extern "C" void kernel_launch(void* const* d_in, const int* in_sizes, int n_in,
                              void* d_out, int out_size, void* d_ws, size_t ws_size,
                              hipStream_t stream)
{
    const float* p0     = (const float*)d_in[0];
    const float* p1     = (const float*)d_in[1];
    const float* p2     = (const float*)d_in[2];
    const float* boxes  = (const float*)d_in[3];
    const int*   labels = (const int*)d_in[4];

    // zero the single-scalar output (memset node; harness does not re-zero
    // between timed replays)
    hipMemsetAsync(d_out, 0, sizeof(float), stream);

    fused_all<<<400, 256, 0, stream>>>(p0, p1, p2, boxes, labels,
                                       (float*)d_out);
}

// Round 10
// 14.121 us; speedup vs baseline: 1.4328x; 1.4328x over previous
//
#include <hip/hip_runtime.h>
#include <math.h>

#define EPSF 1e-7f

__constant__ float c_anch[3][3][2] = {
    {{80.f,104.f},{128.f,240.f},{264.f,184.f}},
    {{480.f,976.f},{992.f,720.f},{944.f,1904.f}},
    {{3712.f,2880.f},{4992.f,6336.f},{11936.f,10432.f}}
};
__constant__ float c_stride[3] = {8.f, 16.f, 32.f};
__constant__ float c_bal[3]    = {4.f, 1.f, 0.4f};
__constant__ int   c_HW[3]     = {6400, 1600, 400};
__constant__ int   c_W[3]      = {80, 40, 20};

__device__ __forceinline__ float bce0(float x) {
    // BCE with target 0: max(x,0) + log(1+exp(-|x|))
    return fmaxf(x, 0.f) + __logf(1.f + __expf(-fabsf(x)));
}

// key-only target build (no logs) — used for the per-block npos recompute
__device__ __forceinline__ int buildKey(float4 bx, int s) {
    float cx = (bx.x + bx.z) * 0.5f, cy = (bx.y + bx.w) * 0.5f;
    float w  = bx.z - bx.x,          h  = bx.w - bx.y;
    float stride = c_stride[s];
    int W = c_W[s];
    int gi = min(max((int)(cy / stride), 0), W - 1);   // row from y
    int gj = min(max((int)(cx / stride), 0), W - 1);   // col from x
    int best = 0; float bm = 1e30f;
    for (int k = 0; k < 3; ++k) {
        float aw = c_anch[s][k][0], ah = c_anch[s][k][1];
        float r0 = w / aw, r1 = h / ah;
        float m = fmaxf(r0, 1.f / r0) * fmaxf(r1, 1.f / r1);
        if (m < bm) { bm = m; best = k; }
    }
    return (best << 20) | (gi << 10) | gj;
}

// ---------------------------------------------------------------------------
// Kernel 1 (400 blocks x 256):
//   all blocks      : 252-float4 slice of the dense objectness reduce
//   blocks [0,384)  : positive targets (register build, no barrier) and an
//                     independent per-block npos[s] recompute (inputs-only)
//   each block writes ONE float scalar partial (already /16, box/npos folded)
// ---------------------------------------------------------------------------
__global__ __launch_bounds__(256) void fused_main(
        const float* __restrict__ p0, const float* __restrict__ p1,
        const float* __restrict__ p2,
        const float* __restrict__ boxes, const int* __restrict__ labels,
        float* __restrict__ part)
{
    __shared__ float red[4][5];          // per-wave {dsum, box, objc, cls, np}

    const int bid  = blockIdx.x;
    const int tid  = threadIdx.x;
    const int lane = tid & 63, wv = tid >> 6;

    const bool isPos = (bid < 384);
    const int s   = bid >> 7;            // valid for pos blocks
    const int b   = (bid >> 3) & 15;
    const int grp = bid & 7;             // target n = grp*4 + wave

    // ---- issue all boxes/labels loads first (pos blocks) ----
    float4 bx; int labl = 0;
    float4 bxn0, bxn1;                   // npos rounds: wave wv covers batches 4wv..4wv+3
    if (isPos) {
        if (lane < 32) {
            bx   = ((const float4*)boxes)[b * 32 + lane];
            labl = labels[b * 32 + lane];
        }
        bxn0 = ((const float4*)boxes)[(wv * 4 + 0 + (lane >> 5)) * 32 + (lane & 31)];
        bxn1 = ((const float4*)boxes)[(wv * 4 + 2 + (lane >> 5)) * 32 + (lane & 31)];
    }

    // ---------------- dense objectness slice (all blocks) ----------------
    float dsum = 0.f;
    {
        int v = bid * 252 + tid;                 // 400*252 = 100800 exactly
        if (tid < 252) {
            int sc, run, off, HW;
            const float* pred;
            if (v < 76800)      { sc = 0; HW = 6400; run = v / 1600;          off = v - run * 1600;         pred = p0; }
            else if (v < 96000) { sc = 1; HW = 1600; int u = v - 76800; run = u / 400; off = u - run * 400; pred = p1; }
            else                { sc = 2; HW = 400;  int u = v - 96000; run = u / 100; off = u - run * 100; pred = p2; }
            int bb = run / 3, a = run - bb * 3;
            const float4* ptr = (const float4*)(pred + (size_t)(bb * 255 + a * 85 + 4) * HW) + off;
            float4 x = *ptr;
            float w = 0.5f * c_bal[sc];
            dsum = w * (bce0(x.x) + bce0(x.y) + bce0(x.z) + bce0(x.w));
        }
    }

    float boxc = 0.f, objc = 0.f, clsp = 0.f;
    float npw = 0.f;                      // this wave's npos contribution (4 batches)
    if (isPos) {
        // ---- per-block npos recompute: 2 rounds x 2 half-wave batches ----
        {
            const int l32 = lane & 31, base = lane & 32;
            int k0 = buildKey(bxn0, s);
            bool dup = false;
            for (int d = 1; d < 32; ++d) {
                int nk = __shfl(k0, base + ((l32 + d) & 31));
                dup |= ((l32 + d) < 32) && (nk == k0);
            }
            npw += (float)__popcll(__ballot(!dup));
            int k1 = buildKey(bxn1, s);
            dup = false;
            for (int d = 1; d < 32; ++d) {
                int nk = __shfl(k1, base + ((l32 + d) & 31));
                dup |= ((l32 + d) < 32) && (nk == k1);
            }
            npw += (float)__popcll(__ballot(!dup));
        }

        // ---- register target build (lanes < 32 hold target `lane`) ----
        int key = 0; float txl = 0.f, tyl = 0.f, twl = 0.f, thl = 0.f;
        {
            float cx = (bx.x + bx.z) * 0.5f, cy = (bx.y + bx.w) * 0.5f;
            float w  = bx.z - bx.x,          h  = bx.w - bx.y;
            float stride = c_stride[s];
            float xg = cx / stride, yg = cy / stride;
            int W = c_W[s];
            int gi = min(max((int)yg, 0), W - 1);   // row from y
            int gj = min(max((int)xg, 0), W - 1);   // col from x
            int best = 0; float bm = 1e30f;
            for (int k = 0; k < 3; ++k) {
                float aw = c_anch[s][k][0], ah = c_anch[s][k][1];
                float r0 = w / aw, r1 = h / ah;
                float m = fmaxf(r0, 1.f / r0) * fmaxf(r1, 1.f / r1);
                if (m < bm) { bm = m; best = k; }
            }
            float aw = c_anch[s][best][0], ah = c_anch[s][best][1];
            key = (best << 20) | (gi << 10) | gj;
            txl = xg - (float)gj;
            tyl = yg - (float)gi;
            twl = __logf(w / (aw + 1e-16f));
            thl = __logf(h / (ah + 1e-16f));
        }

        // this wave's target n: broadcast from lane n, dedup via one ballot
        const int n = grp * 4 + wv;
        int   key_n = __shfl(key, n);
        float tx_n  = __shfl(txl, n);
        float ty_n  = __shfl(tyl, n);
        float tw_n  = __shfl(twl, n);
        float th_n  = __shfl(thl, n);
        int   lab   = __shfl(labl, n);
        unsigned long long dupm =
            __ballot((lane > n) && (lane < 32) && (key == key_n));
        bool win = (dupm == 0ull);        // last-n-wins scatter semantics

        if (win) {
            int a  = key_n >> 20;
            int gi = (key_n >> 10) & 1023;
            int gj = key_n & 1023;
            const int HW = c_HW[s], W = c_W[s];
            int hw = gi * W + gj;
            const float* pred = (s == 0) ? p0 : ((s == 1) ? p1 : p2);
            const float* pb_ = pred + (size_t)(b * 255 + a * 85) * HW + hw;
            const float* pc  = pb_ + (size_t)5 * HW;

            // lane-parallel class logit loads
            float xc0 = pc[(size_t)lane * HW];
            float xc1 = (lane < 16) ? pc[(size_t)(lane + 64) * HW] : 0.f;
            clsp = bce0(xc0) - ((lane == lab) ? xc0 : 0.f);
            if (lane < 16) clsp += bce0(xc1) - ((lane + 64 == lab) ? xc1 : 0.f);

            float px = pb_[0], py = pb_[(size_t)HW];
            float pw = pb_[2 * (size_t)HW], ph = pb_[3 * (size_t)HW];
            float xo = pb_[4 * (size_t)HW];

            // objectness correction:  bal * (0.5*bce0(xo) - xo)
            objc = c_bal[s] * (0.5f * bce0(xo) - xo);

            // CIoU (lane-redundant)
            const float stride = c_stride[s];
            const float aw = c_anch[s][a][0], ah = c_anch[s][a][1];
            float sx = 1.f / (1.f + __expf(-px));
            float sy = 1.f / (1.f + __expf(-py));
            float b1x = (sx + (float)gj) * stride, b1y = (sy + (float)gi) * stride;
            float b1w = __expf(pw) * aw,           b1h = __expf(ph) * ah;
            float b2x = ((float)gj + tx_n) * stride, b2y = ((float)gi + ty_n) * stride;
            float b2w = __expf(tw_n) * aw,           b2h = __expf(th_n) * ah;

            float b1x1 = b1x - b1w * 0.5f, b1x2 = b1x + b1w * 0.5f;
            float b1y1 = b1y - b1h * 0.5f, b1y2 = b1y + b1h * 0.5f;
            float b2x1 = b2x - b2w * 0.5f, b2x2 = b2x + b2w * 0.5f;
            float b2y1 = b2y - b2h * 0.5f, b2y2 = b2y + b2h * 0.5f;
            float iw = fmaxf(fminf(b1x2, b2x2) - fmaxf(b1x1, b2x1), 0.f);
            float ih = fmaxf(fminf(b1y2, b2y2) - fmaxf(b1y1, b2y1), 0.f);
            float inter = iw * ih;
            float uni = b1w * b1h + b2w * b2h - inter + EPSF;
            float iou = inter / uni;
            float cwv = fmaxf(b1x2, b2x2) - fminf(b1x1, b2x1);
            float chv = fmaxf(b1y2, b2y2) - fminf(b1y1, b2y1);
            float c2 = cwv * cwv + chv * chv + EPSF;
            float dx = b2x1 + b2x2 - b1x1 - b1x2;
            float dy = b2y1 + b2y2 - b1y1 - b1y2;
            float rho2 = (dx * dx + dy * dy) * 0.25f;
            float dat = atanf(b2w / (b2h + EPSF)) - atanf(b1w / (b1h + EPSF));
            float v = (4.f / (float)(M_PI * M_PI)) * dat * dat;
            float alpha = v / (v - iou + 1.f + EPSF);
            boxc = 1.f - (iou - (rho2 / c2 + v * alpha));
        }
    }

    // block reduce: {dsum, box, objc, cls, np} -> one scalar per block
    for (int o = 32; o > 0; o >>= 1) {
        dsum += __shfl_down(dsum, o);
        clsp += __shfl_down(clsp, o);
    }
    if (lane == 0) {
        red[wv][0] = dsum; red[wv][1] = boxc; red[wv][2] = objc;
        red[wv][3] = clsp; red[wv][4] = npw;
    }
    __syncthreads();
    if (tid == 0) {
        float d = 0.f, bxs = 0.f, oc = 0.f, cl = 0.f, np = 0.f;
        for (int i = 0; i < 4; ++i) {
            d  += red[i][0]; bxs += red[i][1]; oc += red[i][2];
            cl += red[i][3]; np  += red[i][4];
        }
        // dense-only blocks: bxs=0, np=0 -> box term 0/1 = 0
        part[bid] = (d + oc + 0.5f * cl + bxs / fmaxf(np, 1.f)) * 0.0625f;
    }
}

// ---------------------------------------------------------------------------
// Kernel 2: finalize — sum 400 scalar partials -> out[0] (fixed order)
// ---------------------------------------------------------------------------
__global__ __launch_bounds__(256) void finalize(
        const float* __restrict__ part, float* __restrict__ out)
{
    int tid = threadIdx.x;
    float sum = 0.f;
    for (int i = tid; i < 400; i += 256) sum += part[i];
    for (int o = 32; o > 0; o >>= 1) sum += __shfl_down(sum, o);
    __shared__ float red[4];
    int wv = tid >> 6;
    if ((tid & 63) == 0) red[wv] = sum;
    __syncthreads();
    if (tid == 0)
        out[0] = red[0] + red[1] + red[2] + red[3];
}

extern "C" void kernel_launch(void* const* d_in, const int* in_sizes, int n_in,
                              void* d_out, int out_size, void* d_ws, size_t ws_size,
                              hipStream_t stream)
{
    const float* p0     = (const float*)d_in[0];
    const float* p1     = (const float*)d_in[1];
    const float* p2     = (const float*)d_in[2];
    const float* boxes  = (const float*)d_in[3];
    const int*   labels = (const int*)d_in[4];

    float* part = (float*)d_ws;                 // 400*4 = 1600 B

    fused_main<<<400, 256, 0, stream>>>(p0, p1, p2, boxes, labels, part);
    finalize<<<1, 256, 0, stream>>>(part, (float*)d_out);
}